// Round 15
// baseline (217.115 us; speedup 1.0000x reference)
//
#include <hip/hip_runtime.h>
#include <hip/hip_bf16.h>
#include <stdint.h>

#define B_ 2
#define T_ 2048
#define D_ 2048
#define H_ 16
#define KVH_ 4
#define DK_ 128

typedef __bf16 bf16x8 __attribute__((ext_vector_type(8)));
typedef float f32x4 __attribute__((ext_vector_type(4)));
typedef unsigned short u16x8 __attribute__((ext_vector_type(8)));

typedef __attribute__((address_space(1))) void* gas1_t;
typedef __attribute__((address_space(3))) void* gas3_t;

__device__ __forceinline__ uint16_t f2bf(float f) {
  uint32_t u = __builtin_bit_cast(uint32_t, f);
  u += 0x7FFFu + ((u >> 16) & 1u);
  return (uint16_t)(u >> 16);
}

__device__ __forceinline__ void async16(const void* g, void* l) {
  __builtin_amdgcn_global_load_lds((gas1_t)(uintptr_t)g, (gas3_t)l, 16, 0, 0);
}

// ---------------- all-inputs fp32 -> bf16 convert, one launch ----------------
__global__ __launch_bounds__(256) void k_cvt_all(const float* __restrict__ q,
                                                 const float* __restrict__ k,
                                                 const float* __restrict__ v,
                                                 const float* __restrict__ wq,
                                                 const float* __restrict__ wk,
                                                 const float* __restrict__ wv,
                                                 const float* __restrict__ wo,
                                                 uint16_t* __restrict__ qb,
                                                 uint16_t* __restrict__ kb,
                                                 uint16_t* __restrict__ vb,
                                                 uint16_t* __restrict__ wqb,
                                                 uint16_t* __restrict__ wkb,
                                                 uint16_t* __restrict__ wvb,
                                                 uint16_t* __restrict__ wob) {
  int gb = blockIdx.x;
  const float* s; uint16_t* d; int base;
  if (gb < 4096)        { s = q;  d = qb;  base = 0; }
  else if (gb < 8192)   { s = k;  d = kb;  base = 4096; }
  else if (gb < 12288)  { s = v;  d = vb;  base = 8192; }
  else if (gb < 14336)  { s = wq; d = wqb; base = 12288; }
  else if (gb < 14848)  { s = wk; d = wkb; base = 14336; }
  else if (gb < 15360)  { s = wv; d = wvb; base = 14848; }
  else                  { s = wo; d = wob; base = 15360; }
  int i = (gb - base) * 256 + threadIdx.x;
  const float4* s4 = (const float4*)s;
  float4 a = s4[(size_t)i * 2], b = s4[(size_t)i * 2 + 1];
  union { uint16_t u[8]; uint4 v; } o;
  o.u[0] = f2bf(a.x); o.u[1] = f2bf(a.y); o.u[2] = f2bf(a.z); o.u[3] = f2bf(a.w);
  o.u[4] = f2bf(b.x); o.u[5] = f2bf(b.y); o.u[6] = f2bf(b.z); o.u[7] = f2bf(b.w);
  ((uint4*)d)[i] = o.v;
}

// Bank swizzle (3-bit, b128-optimal) for [row][128B] LDS tiles:
// stored 16B-chunk c holds logical chunk c ^ (row&7). Same involution on the
// global_load_lds SOURCE column and the ds_read address. (row&7 == lr&7.)

// ---------------- bf16 GEMM (out-proj): 128^2 tile, dbuf, XCD-chunked ----------------
__global__ __launch_bounds__(256) void k_gemm_bt(const uint16_t* __restrict__ A,
                                                 const uint16_t* __restrict__ Bm,
                                                 float* __restrict__ C,
                                                 int M, int N, int K) {
  __shared__ uint16_t As[2 * 128 * 64];
  __shared__ uint16_t Bs[2 * 128 * 64];
  const int tid = threadIdx.x;
  const int x = blockIdx.x & 7, j = blockIdx.x >> 3;   // j in 0..63
  const int m0 = (((x >> 1) << 3) + (j & 7)) << 7;     // mpanel 0..31
  const int n0 = (((x & 1) << 3) + (j >> 3)) << 7;     // ntile 0..15
  const int w = tid >> 6, lane = tid & 63;
  const int wr = (w >> 1) << 6, wc = (w & 1) << 6;
  const int lr = lane & 15;
  const int g16 = ((lane >> 4) << 4);
  const int lsw = (lr & 7) << 4;
  f32x4 acc[4][4] = {};
  const int soff = tid * 16;
  const int scol = ((tid & 7) ^ ((tid >> 3) & 7)) << 3;
  const int srow = tid >> 3;
  const int nk = K >> 6;

  auto stage = [&](int t, int buf) {
    char* Ab = (char*)As + (buf << 14);
    char* Bb = (char*)Bs + (buf << 14);
#pragma unroll
    for (int i = 0; i < 4; ++i) {
      int row = i * 32 + srow;
      async16(A + (size_t)(m0 + row) * K + t * 64 + scol, Ab + i * 4096 + soff);
      async16(Bm + (size_t)(n0 + row) * K + t * 64 + scol, Bb + i * 4096 + soff);
    }
  };

  stage(0, 0);
  asm volatile("s_waitcnt vmcnt(0)" ::: "memory");
  __builtin_amdgcn_s_barrier();
  for (int t = 0; t < nk; ++t) {
    const int cur = t & 1;
    if (t + 1 < nk) stage(t + 1, cur ^ 1);
    const char* Ab = (const char*)As + (cur << 14);
    const char* Bb = (const char*)Bs + (cur << 14);
#pragma unroll
    for (int kk2 = 0; kk2 < 128; kk2 += 64) {
      bf16x8 af[4], bfr[4];
      const int cb = (kk2 + g16) ^ lsw;
#pragma unroll
      for (int m = 0; m < 4; ++m)
        af[m] = *(const bf16x8*)(Ab + (wr + m * 16 + lr) * 128 + cb);
#pragma unroll
      for (int n = 0; n < 4; ++n)
        bfr[n] = *(const bf16x8*)(Bb + (wc + n * 16 + lr) * 128 + cb);
#pragma unroll
      for (int m = 0; m < 4; ++m)
#pragma unroll
        for (int n = 0; n < 4; ++n)
          acc[m][n] = __builtin_amdgcn_mfma_f32_16x16x32_bf16(af[m], bfr[n], acc[m][n], 0, 0, 0);
    }
    asm volatile("s_waitcnt vmcnt(0)" ::: "memory");
    __builtin_amdgcn_s_barrier();
  }
  const int r0 = (lane >> 4) << 2;
  const int c = lane & 15;
#pragma unroll
  for (int m = 0; m < 4; ++m)
#pragma unroll
    for (int n = 0; n < 4; ++n)
#pragma unroll
      for (int r = 0; r < 4; ++r)
        C[(size_t)(m0 + wr + m * 16 + r0 + r) * N + n0 + wc + n * 16 + c] = acc[m][n][r];
}

// ---------------- merged QKV projection: dbuf 128^2 tiles, XCD-chunked ----------------
// [0,512):   Q (32m x 16n) -> l2norm*g/sqrt(dk) -> Qn (B,H,T,128)
// [512,640): V (32m x 4n)  -> transpose -> Vt (B,KVH,128,T)
// [640,768): K (32m x 4n)  -> l2norm -> Kn (B,KVH,T,128)
// Same inner structure as k_gemm_bt (measured ~2x the serial-stage version).
__global__ __launch_bounds__(256) void k_proj(const uint16_t* __restrict__ qb,
                                              const uint16_t* __restrict__ kb,
                                              const uint16_t* __restrict__ vb,
                                              const uint16_t* __restrict__ Wqb,
                                              const uint16_t* __restrict__ Wkb,
                                              const uint16_t* __restrict__ Wvb,
                                              uint16_t* __restrict__ Qn,
                                              uint16_t* __restrict__ Kn,
                                              uint16_t* __restrict__ Vt,
                                              const float* __restrict__ g) {
  __shared__ uint16_t As[2 * 128 * 64];   // 32 KB
  __shared__ uint16_t Bs[2 * 128 * 64];   // 32 KB; V-epilogue tr[128][132] aliases As/Bs
  __shared__ float ssred[2][128];
  const int bid = blockIdx.x;
  int mode, lb;
  if (bid < 512)      { mode = 0; lb = bid; }          // Q
  else if (bid < 640) { mode = 2; lb = bid - 512; }    // V
  else                { mode = 1; lb = bid - 640; }    // K
  const uint16_t* A;
  const uint16_t* Bw;
  if (mode == 0)      { A = qb; Bw = Wqb; }
  else if (mode == 1) { A = kb; Bw = Wkb; }
  else                { A = vb; Bw = Wvb; }
  int mpanel, ntile;
  {
    int x = lb & 7, jj = lb >> 3;
    if (mode == 0) { mpanel = ((x >> 1) << 3) + (jj & 7); ntile = ((x & 1) << 3) + (jj >> 3); }
    else           { mpanel = ((x >> 1) << 3) + (jj & 7); ntile = ((x & 1) << 1) + (jj >> 3); }
  }
  const int m0 = mpanel << 7;
  const int n0 = ntile << 7;
  const int tid = threadIdx.x;
  const int w = tid >> 6, lane = tid & 63;
  const int wr = (w >> 1) << 6, wc = (w & 1) << 6;
  const int lr = lane & 15;
  const int g16 = ((lane >> 4) << 4);
  const int lsw = (lr & 7) << 4;
  f32x4 acc[4][4] = {};
  const int soff = tid * 16;
  const int scol = ((tid & 7) ^ ((tid >> 3) & 7)) << 3;
  const int srow = tid >> 3;
  const int g4 = lane >> 4;
  const int r04 = g4 << 2;

  auto stage = [&](int t, int buf) {
    char* Ab = (char*)As + (buf << 14);
    char* Bb = (char*)Bs + (buf << 14);
#pragma unroll
    for (int i = 0; i < 4; ++i) {
      int row = i * 32 + srow;
      async16(A + (size_t)(m0 + row) * 2048 + t * 64 + scol, Ab + i * 4096 + soff);
      async16(Bw + (size_t)(n0 + row) * 2048 + t * 64 + scol, Bb + i * 4096 + soff);
    }
  };

  stage(0, 0);
  asm volatile("s_waitcnt vmcnt(0)" ::: "memory");
  __builtin_amdgcn_s_barrier();
  for (int t = 0; t < 32; ++t) {
    const int cur = t & 1;
    if (t + 1 < 32) stage(t + 1, cur ^ 1);
    const char* Ab = (const char*)As + (cur << 14);
    const char* Bb = (const char*)Bs + (cur << 14);
#pragma unroll
    for (int kk2 = 0; kk2 < 128; kk2 += 64) {
      bf16x8 af[4], bfr[4];
      const int cb = (kk2 + g16) ^ lsw;
#pragma unroll
      for (int m = 0; m < 4; ++m)
        af[m] = *(const bf16x8*)(Ab + (wr + m * 16 + lr) * 128 + cb);
#pragma unroll
      for (int n = 0; n < 4; ++n)
        bfr[n] = *(const bf16x8*)(Bb + (wc + n * 16 + lr) * 128 + cb);
#pragma unroll
      for (int m = 0; m < 4; ++m)
#pragma unroll
        for (int n = 0; n < 4; ++n)
          acc[m][n] = __builtin_amdgcn_mfma_f32_16x16x32_bf16(af[m], bfr[n], acc[m][n], 0, 0, 0);
    }
    asm volatile("s_waitcnt vmcnt(0)" ::: "memory");
    __builtin_amdgcn_s_barrier();
  }

  const int b = m0 >> 11;
  const int t0 = m0 & (T_ - 1);
  const int h = n0 >> 7;

  if (mode <= 1) {
    // ---- fused l2norm epilogue: rows are complete head vectors (BN=128=DK) ----
    float ss[4][4];
#pragma unroll
    for (int m = 0; m < 4; ++m)
#pragma unroll
      for (int r = 0; r < 4; ++r) {
        float s = 0.f;
#pragma unroll
        for (int n = 0; n < 4; ++n) s += acc[m][n][r] * acc[m][n][r];
        ss[m][r] = s;
      }
#pragma unroll
    for (int mask = 1; mask < 16; mask <<= 1)
#pragma unroll
      for (int m = 0; m < 4; ++m)
#pragma unroll
        for (int r = 0; r < 4; ++r) ss[m][r] += __shfl_xor(ss[m][r], mask);
#pragma unroll
    for (int m = 0; m < 4; ++m)
#pragma unroll
      for (int r = 0; r < 4; ++r)
        if (lr == (m << 2 | r)) ssred[w & 1][wr + m * 16 + g4 * 4 + r] = ss[m][r];
    __syncthreads();
    uint16_t* outp = (mode == 0) ? Qn : Kn;
    const int NHv = (mode == 0) ? H_ : KVH_;
    const float gmul = (mode == 0) ? g[h] * 0.08838834764831845f : 1.0f;  // fold 1/sqrt(128)
#pragma unroll
    for (int m = 0; m < 4; ++m)
#pragma unroll
      for (int r = 0; r < 4; ++r) {
        int row = wr + m * 16 + g4 * 4 + r;
        float tot = ssred[0][row] + ssred[1][row];
        float scl = gmul / fmaxf(sqrtf(tot), 1e-12f);
        size_t base = ((size_t)(b * NHv + h) * T_ + (t0 + row)) * 128;
#pragma unroll
        for (int n = 0; n < 4; ++n)
          outp[base + wc + n * 16 + lr] = f2bf(acc[m][n][r] * scl);
      }
  } else {
    // ---- fused V-transpose epilogue (aliases As/Bs; all staging complete) ----
    uint16_t* tr = (uint16_t*)As;  // [col 0..127][trow 0..127], stride 132
#pragma unroll
    for (int m = 0; m < 4; ++m)
#pragma unroll
      for (int n = 0; n < 4; ++n)
#pragma unroll
        for (int r = 0; r < 4; ++r)
          tr[(wc + n * 16 + lr) * 132 + (wr + m * 16 + r04 + r)] = f2bf(acc[m][n][r]);
    __syncthreads();
    const int qd = tid & 3;
#pragma unroll
    for (int dd = 0; dd < 2; ++dd) {
      int d = (tid >> 2) + dd * 64;
      uint16_t* dst = Vt + ((size_t)(b * KVH_ + h) * 128 + d) * T_ + t0 + qd * 32;
      const uint16_t* srcl = &tr[d * 132 + qd * 32];
#pragma unroll
      for (int j = 0; j < 8; ++j)
        *(ushort4*)(dst + j * 4) = *(const ushort4*)(srcl + j * 4);
    }
  }
}

// ---------------- causal GQA flash attention, paired q-tiles, dbuf K/V ----------------
__global__ __launch_bounds__(256) void k_attn(const uint16_t* __restrict__ Qn,
                                              const uint16_t* __restrict__ Kn,
                                              const uint16_t* __restrict__ Vt,
                                              uint16_t* __restrict__ Y) {
  __shared__ uint16_t Ks[2 * 64 * 128];
  __shared__ uint16_t Vs[2 * 128 * 64];
  __shared__ uint16_t Ps[4 * 16 * 32];
  const int npair = T_ / 128;              // 16
  const int pair_id = blockIdx.x % npair;
  const int bh = blockIdx.x / npair;
  const int h = bh % H_;
  const int b = bh / H_;
  const int kvh = h >> 2;
  const int qtA = pair_id;                 // light tile
  const int qtB = (T_ / 64) - 1 - pair_id; // heavy tile
  const uint16_t* Qh = Qn + ((size_t)(b * H_ + h) * T_) * 128;
  const uint16_t* Kh = Kn + ((size_t)(b * KVH_ + kvh) * T_) * 128;
  const uint16_t* Vh = Vt + ((size_t)(b * KVH_ + kvh) * 128) * T_;
  const int tid = threadIdx.x;
  const int w = tid >> 6, lane = tid & 63;
  const int lr = lane & 15;
  const int lk2 = (lane >> 4) << 4;
  const int r0 = (lane >> 4) << 2;
  const int qwA = qtA * 64 + w * 16;
  const int qwB = qtB * 64 + w * 16;
  char* Psw = (char*)Ps + w * 1024;

  bf16x8 qfA[4], qfB[4];
#pragma unroll
  for (int dblk = 0; dblk < 4; ++dblk) {
    qfA[dblk] = *(const bf16x8*)&Qh[(size_t)(qwA + lr) * 128 + dblk * 32 + (lk2 >> 1)];
    qfB[dblk] = *(const bf16x8*)&Qh[(size_t)(qwB + lr) * 128 + dblk * 32 + (lk2 >> 1)];
  }
  union { uint16_t u[8]; bf16x8 v; } ou;
#pragma unroll
  for (int j = 0; j < 8; ++j) ou.u[j] = 0x3F80;
  const bf16x8 ones = ou.v;
  f32x4 oA[8] = {}, oB[8] = {};
  f32x4 sumA = {}, sumB = {};

  auto stageKV = [&](int tile, int buf) {
    const int kv0 = tile * 64;
    char* Kb = (char*)Ks + (buf << 14);
    char* Vb = (char*)Vs + (buf << 14);
#pragma unroll
    for (int i = 0; i < 4; ++i) {
      int off = i * 4096 + tid * 16;
      int krow = off >> 8;
      int kchunk = (off >> 4) & 15;
      int kcol = (kchunk ^ (krow & 7)) << 3;
      async16(Kh + (size_t)(kv0 + krow) * 128 + kcol, Kb + off);
      int vrow = off >> 7;
      int vchunk = (off >> 4) & 7;
      int vcol = (vchunk ^ (vrow & 7)) << 3;
      async16(Vh + (size_t)vrow * T_ + kv0 + vcol, Vb + off);
    }
  };

  auto tilecompute = [&](const bf16x8* qf, f32x4* o, f32x4* sum, int qw, int kv0, int cur) {
    const char* Kb = (const char*)Ks + (cur << 14);
    const char* Vb = (const char*)Vs + (cur << 14);
#pragma unroll
    for (int prr = 0; prr < 2; ++prr) {
#pragma unroll
      for (int kbi = 0; kbi < 2; ++kbi) {
        int kb = prr * 2 + kbi;
        f32x4 s = {};
#pragma unroll
        for (int dblk = 0; dblk < 4; ++dblk) {
          bf16x8 kf = *(const bf16x8*)(Kb +
              ((kb * 16 + lr) << 8) + ((dblk * 64 + lk2) ^ ((lr & 7) << 4)));
          s = __builtin_amdgcn_mfma_f32_16x16x32_bf16(qf[dblk], kf, s, 0, 0, 0);
        }
        int kval = kv0 + kb * 16 + lr;
#pragma unroll
        for (int r = 0; r < 4; ++r) {
          float pv = (kval <= qw + r0 + r) ? __expf(s[r]) : 0.0f;
          *(uint16_t*)(Psw + (r0 + r) * 64 + (((kbi * 16 + lr) * 2) ^ (r << 4))) = f2bf(pv);
        }
      }
      asm volatile("s_waitcnt lgkmcnt(0)" ::: "memory");
      bf16x8 pa = *(const bf16x8*)(Psw + lr * 64 + (lk2 ^ ((lr & 3) << 4)));
#pragma unroll
      for (int dblk = 0; dblk < 8; ++dblk) {
        bf16x8 vf = *(const bf16x8*)(Vb +
            ((dblk * 16 + lr) << 7) + ((prr * 64 + lk2) ^ ((lr & 7) << 4)));
        o[dblk] = __builtin_amdgcn_mfma_f32_16x16x32_bf16(pa, vf, o[dblk], 0, 0, 0);
      }
      *sum = __builtin_amdgcn_mfma_f32_16x16x32_bf16(pa, ones, *sum, 0, 0, 0);
    }
  };

  stageKV(0, 0);
  asm volatile("s_waitcnt vmcnt(0)" ::: "memory");
  __builtin_amdgcn_s_barrier();
  for (int tile = 0; tile <= qtB; ++tile) {
    const int cur = tile & 1;
    if (tile < qtB) stageKV(tile + 1, cur ^ 1);   // prefetch under compute
    const int kv0 = tile * 64;
    tilecompute(qfB, oB, &sumB, qwB, kv0, cur);
    if (tile <= qtA) tilecompute(qfA, oA, &sumA, qwA, kv0, cur);
    asm volatile("s_waitcnt vmcnt(0)" ::: "memory");  // prefetch landed (cheap now)
    __builtin_amdgcn_s_barrier();
  }

  auto writeout = [&](const f32x4* o, const f32x4& sum, int qw) {
#pragma unroll
    for (int r = 0; r < 4; ++r) {
      float inv = 1.0f / sum[r];
      size_t base = ((size_t)b * T_ + (qw + r0 + r)) * D_ + h * 128 + lr;
#pragma unroll
      for (int dblk = 0; dblk < 8; ++dblk)
        Y[base + dblk * 16] = f2bf(o[dblk][r] * inv);
    }
  };
  writeout(oA, sumA, qwA);
  writeout(oB, sumB, qwB);
}

extern "C" void kernel_launch(void* const* d_in, const int* in_sizes, int n_in,
                              void* d_out, int out_size, void* d_ws, size_t ws_size,
                              hipStream_t stream) {
  (void)in_sizes; (void)n_in; (void)out_size; (void)ws_size;
  const float* q  = (const float*)d_in[0];
  const float* k  = (const float*)d_in[1];
  const float* v  = (const float*)d_in[2];
  const float* Wq = (const float*)d_in[3];
  const float* Wk = (const float*)d_in[4];
  const float* Wv = (const float*)d_in[5];
  const float* Wo = (const float*)d_in[6];
  const float* g  = (const float*)d_in[7];
  float* out = (float*)d_out;
  char* ws = (char*)d_ws;
  const size_t MB = 1ull << 20;
  uint16_t* qb  = (uint16_t*)(ws);             // 16MB; reused as Y after k_proj
  uint16_t* kb  = (uint16_t*)(ws + 16 * MB);   // 16MB
  uint16_t* vb  = (uint16_t*)(ws + 32 * MB);   // 16MB
  uint16_t* Wqb = (uint16_t*)(ws + 48 * MB);   // 8MB
  uint16_t* Wkb = (uint16_t*)(ws + 56 * MB);   // 2MB
  uint16_t* Wvb = (uint16_t*)(ws + 58 * MB);   // 2MB
  uint16_t* Kn  = (uint16_t*)(ws + 60 * MB);   // 4MB
  uint16_t* Vtb = (uint16_t*)(ws + 64 * MB);   // 4MB
  uint16_t* Wob = (uint16_t*)(ws + 68 * MB);   // 8MB (ws high-water: 76MB)
  uint16_t* Qn  = (uint16_t*)d_out;            // 16MB scratch in d_out; dead
                                               // before final GEMM overwrites it
  uint16_t* Y   = qb;

  // 1) convert all seven fp32 inputs in one launch
  k_cvt_all<<<17408, 256, 0, stream>>>(q, k, v, Wq, Wk, Wv, Wo,
                                       qb, kb, vb, Wqb, Wkb, Wvb, Wob);
  // 2) merged Q/K/V projection, dbuf 128^2 structure (768 blocks: 512 Q + 128 V + 128 K)
  k_proj<<<768, 256, 0, stream>>>(qb, kb, vb, Wqb, Wkb, Wvb, Qn, Kn, Vtb, g);
  // 3) attention (reads Qn from d_out, writes Y)
  k_attn<<<B_ * H_ * (T_ / 128), 256, 0, stream>>>(Qn, Kn, Vtb, Y);
  // 4) output projection: 128^2 dbuf + XCD-chunked + 3-bit swizzle (512 blocks)
  k_gemm_bt<<<(B_ * T_ / 128) * (D_ / 128), 256, 0, stream>>>(Y, Wob, out, B_ * T_, D_, D_);
}

// Round 16
// 195.484 us; speedup vs baseline: 1.1107x; 1.1107x over previous
//
#include <hip/hip_runtime.h>
#include <hip/hip_bf16.h>
#include <stdint.h>

#define B_ 2
#define T_ 2048
#define D_ 2048
#define H_ 16
#define KVH_ 4
#define DK_ 128

typedef __bf16 bf16x8 __attribute__((ext_vector_type(8)));
typedef float f32x4 __attribute__((ext_vector_type(4)));
typedef unsigned short u16x8 __attribute__((ext_vector_type(8)));

typedef __attribute__((address_space(1))) void* gas1_t;
typedef __attribute__((address_space(3))) void* gas3_t;

__device__ __forceinline__ uint16_t f2bf(float f) {
  uint32_t u = __builtin_bit_cast(uint32_t, f);
  u += 0x7FFFu + ((u >> 16) & 1u);
  return (uint16_t)(u >> 16);
}

__device__ __forceinline__ void async16(const void* g, void* l) {
  __builtin_amdgcn_global_load_lds((gas1_t)(uintptr_t)g, (gas3_t)l, 16, 0, 0);
}

// ---------------- all-inputs fp32 -> bf16 convert, one launch ----------------
__global__ __launch_bounds__(256) void k_cvt_all(const float* __restrict__ q,
                                                 const float* __restrict__ k,
                                                 const float* __restrict__ v,
                                                 const float* __restrict__ wq,
                                                 const float* __restrict__ wk,
                                                 const float* __restrict__ wv,
                                                 const float* __restrict__ wo,
                                                 uint16_t* __restrict__ qb,
                                                 uint16_t* __restrict__ kb,
                                                 uint16_t* __restrict__ vb,
                                                 uint16_t* __restrict__ wqb,
                                                 uint16_t* __restrict__ wkb,
                                                 uint16_t* __restrict__ wvb,
                                                 uint16_t* __restrict__ wob) {
  int gb = blockIdx.x;
  const float* s; uint16_t* d; int base;
  if (gb < 4096)        { s = q;  d = qb;  base = 0; }
  else if (gb < 8192)   { s = k;  d = kb;  base = 4096; }
  else if (gb < 12288)  { s = v;  d = vb;  base = 8192; }
  else if (gb < 14336)  { s = wq; d = wqb; base = 12288; }
  else if (gb < 14848)  { s = wk; d = wkb; base = 14336; }
  else if (gb < 15360)  { s = wv; d = wvb; base = 14848; }
  else                  { s = wo; d = wob; base = 15360; }
  int i = (gb - base) * 256 + threadIdx.x;
  const float4* s4 = (const float4*)s;
  float4 a = s4[(size_t)i * 2], b = s4[(size_t)i * 2 + 1];
  union { uint16_t u[8]; uint4 v; } o;
  o.u[0] = f2bf(a.x); o.u[1] = f2bf(a.y); o.u[2] = f2bf(a.z); o.u[3] = f2bf(a.w);
  o.u[4] = f2bf(b.x); o.u[5] = f2bf(b.y); o.u[6] = f2bf(b.z); o.u[7] = f2bf(b.w);
  ((uint4*)d)[i] = o.v;
}

// Bank swizzle (3-bit, b128-optimal) for [row][128B] LDS tiles:
// stored 16B-chunk c holds logical chunk c ^ (row&7). A wave's 16-lane service
// group then covers all 8 bank-quads exactly twice (2-way = free). Same
// involution on the global_load_lds SOURCE column and the ds_read address.
// (Rows read are base+lr with base%16==0, so row&7 == lr&7.)

// ---------------- bf16 GEMM (out-proj): 128^2 tile, dbuf, XCD-chunked ----------------
__global__ __launch_bounds__(256) void k_gemm_bt(const uint16_t* __restrict__ A,
                                                 const uint16_t* __restrict__ Bm,
                                                 float* __restrict__ C,
                                                 int M, int N, int K) {
  __shared__ uint16_t As[2 * 128 * 64];
  __shared__ uint16_t Bs[2 * 128 * 64];
  const int tid = threadIdx.x;
  const int x = blockIdx.x & 7, j = blockIdx.x >> 3;   // j in 0..63
  const int m0 = (((x >> 1) << 3) + (j & 7)) << 7;     // mpanel 0..31
  const int n0 = (((x & 1) << 3) + (j >> 3)) << 7;     // ntile 0..15
  const int w = tid >> 6, lane = tid & 63;
  const int wr = (w >> 1) << 6, wc = (w & 1) << 6;
  const int lr = lane & 15;
  const int g16 = ((lane >> 4) << 4);
  const int lsw = (lr & 7) << 4;
  f32x4 acc[4][4] = {};
  const int soff = tid * 16;
  const int scol = ((tid & 7) ^ ((tid >> 3) & 7)) << 3;
  const int srow = tid >> 3;
  const int nk = K >> 6;

  auto stage = [&](int t, int buf) {
    char* Ab = (char*)As + (buf << 14);
    char* Bb = (char*)Bs + (buf << 14);
#pragma unroll
    for (int i = 0; i < 4; ++i) {
      int row = i * 32 + srow;
      async16(A + (size_t)(m0 + row) * K + t * 64 + scol, Ab + i * 4096 + soff);
      async16(Bm + (size_t)(n0 + row) * K + t * 64 + scol, Bb + i * 4096 + soff);
    }
  };

  stage(0, 0);
  asm volatile("s_waitcnt vmcnt(0)" ::: "memory");
  __builtin_amdgcn_s_barrier();
  for (int t = 0; t < nk; ++t) {
    const int cur = t & 1;
    if (t + 1 < nk) stage(t + 1, cur ^ 1);
    const char* Ab = (const char*)As + (cur << 14);
    const char* Bb = (const char*)Bs + (cur << 14);
#pragma unroll
    for (int kk2 = 0; kk2 < 128; kk2 += 64) {
      bf16x8 af[4], bfr[4];
      const int cb = (kk2 + g16) ^ lsw;
#pragma unroll
      for (int m = 0; m < 4; ++m)
        af[m] = *(const bf16x8*)(Ab + (wr + m * 16 + lr) * 128 + cb);
#pragma unroll
      for (int n = 0; n < 4; ++n)
        bfr[n] = *(const bf16x8*)(Bb + (wc + n * 16 + lr) * 128 + cb);
#pragma unroll
      for (int m = 0; m < 4; ++m)
#pragma unroll
        for (int n = 0; n < 4; ++n)
          acc[m][n] = __builtin_amdgcn_mfma_f32_16x16x32_bf16(af[m], bfr[n], acc[m][n], 0, 0, 0);
    }
    asm volatile("s_waitcnt vmcnt(0)" ::: "memory");
    __builtin_amdgcn_s_barrier();
  }
  const int r0 = (lane >> 4) << 2;
  const int c = lane & 15;
#pragma unroll
  for (int m = 0; m < 4; ++m)
#pragma unroll
    for (int n = 0; n < 4; ++n)
#pragma unroll
      for (int r = 0; r < 4; ++r)
        C[(size_t)(m0 + wr + m * 16 + r0 + r) * N + n0 + wc + n * 16 + c] = acc[m][n][r];
}

// ---------------- merged QKV projection, balanced 512-block grid ----------------
// [0,256):   Q, M-paired 256x128 tiles, XCD-chunked  (heavy)
// [256,384): V, unpaired 128x128 -> transpose        (light)
// [384,512): K, unpaired 128x128 -> l2norm           (light)
__global__ __launch_bounds__(256, 2) void k_proj(const uint16_t* __restrict__ qb,
                                                 const uint16_t* __restrict__ kb,
                                                 const uint16_t* __restrict__ vb,
                                                 const uint16_t* __restrict__ Wqb,
                                                 const uint16_t* __restrict__ Wkb,
                                                 const uint16_t* __restrict__ Wvb,
                                                 uint16_t* __restrict__ Qn,
                                                 uint16_t* __restrict__ Kn,
                                                 uint16_t* __restrict__ Vt,
                                                 const float* __restrict__ g) {
  __shared__ char smem[49152];   // Q: Aa/Ab/B 16KB each. KV: A@0, B@16384. tr aliases.
  __shared__ float ssred[2][256];
  const int bid = blockIdx.x;
  const int tid = threadIdx.x;
  const int w = tid >> 6, lane = tid & 63;
  const int wr = (w >> 1) << 6, wc = (w & 1) << 6;
  const int lr = lane & 15;
  const int g16 = ((lane >> 4) << 4);
  const int lsw = (lr & 7) << 4;
  const int soff = tid * 16;
  const int scol = ((tid & 7) ^ ((tid >> 3) & 7)) << 3;
  const int srow = tid >> 3;
  const int g4 = lane >> 4;
  const int r04 = g4 << 2;

  if (bid < 256) {
    // ================= Q: M-paired =================
    const uint16_t* A = qb;
    const uint16_t* Bw = Wqb;
    const int x = bid & 7, jj = bid >> 3;
    const int m0 = (((x >> 1) << 2) + (jj & 3)) << 8;      // 16 mpanels of 256 rows
    const int n0 = (((x & 1) << 3) + (jj >> 2)) << 7;      // 16 ntiles
    f32x4 acc[8][4] = {};
    for (int t = 0; t < 32; ++t) {
#pragma unroll
      for (int i = 0; i < 4; ++i) {
        int row = i * 32 + srow;
        async16(A + (size_t)(m0 + row) * 2048 + t * 64 + scol, smem + i * 4096 + soff);
        async16(A + (size_t)(m0 + 128 + row) * 2048 + t * 64 + scol, smem + 16384 + i * 4096 + soff);
        async16(Bw + (size_t)(n0 + row) * 2048 + t * 64 + scol, smem + 32768 + i * 4096 + soff);
      }
      __syncthreads();
#pragma unroll
      for (int kk2 = 0; kk2 < 128; kk2 += 64) {
        bf16x8 aA[4], aB[4], bfr[4];
        const int cb = (kk2 + g16) ^ lsw;
#pragma unroll
        for (int m = 0; m < 4; ++m) {
          aA[m] = *(const bf16x8*)(smem + (wr + m * 16 + lr) * 128 + cb);
          aB[m] = *(const bf16x8*)(smem + 16384 + (wr + m * 16 + lr) * 128 + cb);
        }
#pragma unroll
        for (int n = 0; n < 4; ++n)
          bfr[n] = *(const bf16x8*)(smem + 32768 + (wc + n * 16 + lr) * 128 + cb);
#pragma unroll
        for (int m = 0; m < 4; ++m)
#pragma unroll
          for (int n = 0; n < 4; ++n) {
            acc[m][n] = __builtin_amdgcn_mfma_f32_16x16x32_bf16(aA[m], bfr[n], acc[m][n], 0, 0, 0);
            acc[m + 4][n] = __builtin_amdgcn_mfma_f32_16x16x32_bf16(aB[m], bfr[n], acc[m + 4][n], 0, 0, 0);
          }
      }
      __syncthreads();
    }
    // ---- fused l2norm*g epilogue over 256 rows ----
    const int b = m0 >> 11;
    const int t0 = m0 & (T_ - 1);
    const int h = n0 >> 7;
    float ss[8][4];
#pragma unroll
    for (int m = 0; m < 8; ++m)
#pragma unroll
      for (int r = 0; r < 4; ++r) {
        float s = 0.f;
#pragma unroll
        for (int n = 0; n < 4; ++n) s += acc[m][n][r] * acc[m][n][r];
        ss[m][r] = s;
      }
#pragma unroll
    for (int mask = 1; mask < 16; mask <<= 1)
#pragma unroll
      for (int m = 0; m < 8; ++m)
#pragma unroll
        for (int r = 0; r < 4; ++r) ss[m][r] += __shfl_xor(ss[m][r], mask);
#pragma unroll
    for (int m = 0; m < 8; ++m)
#pragma unroll
      for (int r = 0; r < 4; ++r)
        if (lr == (((m & 3) << 2) | r))
          ssred[w & 1][(m >> 2) * 128 + wr + (m & 3) * 16 + g4 * 4 + r] = ss[m][r];
    __syncthreads();
    const float gmul = g[h] * 0.08838834764831845f;   // fold 1/sqrt(128)
#pragma unroll
    for (int m = 0; m < 8; ++m)
#pragma unroll
      for (int r = 0; r < 4; ++r) {
        int row = (m >> 2) * 128 + wr + (m & 3) * 16 + g4 * 4 + r;
        float tot = ssred[0][row] + ssred[1][row];
        float scl = gmul / fmaxf(sqrtf(tot), 1e-12f);
        size_t base = ((size_t)(b * H_ + h) * T_ + (t0 + row)) * 128;
#pragma unroll
        for (int n = 0; n < 4; ++n)
          Qn[base + wc + n * 16 + lr] = f2bf(acc[m][n][r] * scl);
      }
  } else {
    // ================= K/V: unpaired 128^2 =================
    const int mode = (bid < 384) ? 2 : 1;          // 2=V, 1=K
    const int lb = (mode == 2) ? bid - 256 : bid - 384;
    const uint16_t* A = (mode == 2) ? vb : kb;
    const uint16_t* Bw = (mode == 2) ? Wvb : Wkb;
    const int x = lb & 7, jj = lb >> 3;            // jj 0..15
    const int m0 = (((x >> 1) << 3) + (jj & 7)) << 7;   // 32 mpanels of 128 rows
    const int n0 = (((x & 1) << 1) + (jj >> 3)) << 7;   // 4 ntiles
    f32x4 acc[4][4] = {};
    for (int t = 0; t < 32; ++t) {
#pragma unroll
      for (int i = 0; i < 4; ++i) {
        int row = i * 32 + srow;
        async16(A + (size_t)(m0 + row) * 2048 + t * 64 + scol, smem + i * 4096 + soff);
        async16(Bw + (size_t)(n0 + row) * 2048 + t * 64 + scol, smem + 16384 + i * 4096 + soff);
      }
      __syncthreads();
#pragma unroll
      for (int kk2 = 0; kk2 < 128; kk2 += 64) {
        bf16x8 af[4], bfr[4];
        const int cb = (kk2 + g16) ^ lsw;
#pragma unroll
        for (int m = 0; m < 4; ++m)
          af[m] = *(const bf16x8*)(smem + (wr + m * 16 + lr) * 128 + cb);
#pragma unroll
        for (int n = 0; n < 4; ++n)
          bfr[n] = *(const bf16x8*)(smem + 16384 + (wc + n * 16 + lr) * 128 + cb);
#pragma unroll
        for (int m = 0; m < 4; ++m)
#pragma unroll
          for (int n = 0; n < 4; ++n)
            acc[m][n] = __builtin_amdgcn_mfma_f32_16x16x32_bf16(af[m], bfr[n], acc[m][n], 0, 0, 0);
      }
      __syncthreads();
    }
    const int b = m0 >> 11;
    const int t0 = m0 & (T_ - 1);
    const int h = n0 >> 7;
    if (mode == 1) {
      // ---- fused l2norm epilogue (K) ----
      float ss[4][4];
#pragma unroll
      for (int m = 0; m < 4; ++m)
#pragma unroll
        for (int r = 0; r < 4; ++r) {
          float s = 0.f;
#pragma unroll
          for (int n = 0; n < 4; ++n) s += acc[m][n][r] * acc[m][n][r];
          ss[m][r] = s;
        }
#pragma unroll
      for (int mask = 1; mask < 16; mask <<= 1)
#pragma unroll
        for (int m = 0; m < 4; ++m)
#pragma unroll
          for (int r = 0; r < 4; ++r) ss[m][r] += __shfl_xor(ss[m][r], mask);
#pragma unroll
      for (int m = 0; m < 4; ++m)
#pragma unroll
        for (int r = 0; r < 4; ++r)
          if (lr == (m << 2 | r)) ssred[w & 1][wr + m * 16 + g4 * 4 + r] = ss[m][r];
      __syncthreads();
#pragma unroll
      for (int m = 0; m < 4; ++m)
#pragma unroll
        for (int r = 0; r < 4; ++r) {
          int row = wr + m * 16 + g4 * 4 + r;
          float tot = ssred[0][row] + ssred[1][row];
          float scl = 1.0f / fmaxf(sqrtf(tot), 1e-12f);
          size_t base = ((size_t)(b * KVH_ + h) * T_ + (t0 + row)) * 128;
#pragma unroll
          for (int n = 0; n < 4; ++n)
            Kn[base + wc + n * 16 + lr] = f2bf(acc[m][n][r] * scl);
        }
    } else {
      // ---- fused V-transpose epilogue ----
      uint16_t* tr = (uint16_t*)smem;  // [col 0..127][trow 0..127], stride 132
#pragma unroll
      for (int m = 0; m < 4; ++m)
#pragma unroll
        for (int n = 0; n < 4; ++n)
#pragma unroll
          for (int r = 0; r < 4; ++r)
            tr[(wc + n * 16 + lr) * 132 + (wr + m * 16 + r04 + r)] = f2bf(acc[m][n][r]);
      __syncthreads();
      const int qd = tid & 3;
#pragma unroll
      for (int dd = 0; dd < 2; ++dd) {
        int d = (tid >> 2) + dd * 64;
        uint16_t* dst = Vt + ((size_t)(b * KVH_ + h) * 128 + d) * T_ + t0 + qd * 32;
        const uint16_t* srcl = &tr[d * 132 + qd * 32];
#pragma unroll
        for (int j = 0; j < 8; ++j)
          *(ushort4*)(dst + j * 4) = *(const ushort4*)(srcl + j * 4);
      }
    }
  }
}

// ---------------- causal GQA flash attention, paired q-tiles, dbuf K/V, setprio ----------------
__global__ __launch_bounds__(256) void k_attn(const uint16_t* __restrict__ Qn,
                                              const uint16_t* __restrict__ Kn,
                                              const uint16_t* __restrict__ Vt,
                                              uint16_t* __restrict__ Y) {
  __shared__ uint16_t Ks[2 * 64 * 128];
  __shared__ uint16_t Vs[2 * 128 * 64];
  __shared__ uint16_t Ps[4 * 16 * 32];
  const int npair = T_ / 128;              // 16
  const int pair_id = blockIdx.x % npair;
  const int bh = blockIdx.x / npair;
  const int h = bh % H_;
  const int b = bh / H_;
  const int kvh = h >> 2;
  const int qtA = pair_id;                 // light tile
  const int qtB = (T_ / 64) - 1 - pair_id; // heavy tile
  const uint16_t* Qh = Qn + ((size_t)(b * H_ + h) * T_) * 128;
  const uint16_t* Kh = Kn + ((size_t)(b * KVH_ + kvh) * T_) * 128;
  const uint16_t* Vh = Vt + ((size_t)(b * KVH_ + kvh) * 128) * T_;
  const int tid = threadIdx.x;
  const int w = tid >> 6, lane = tid & 63;
  const int lr = lane & 15;
  const int lk2 = (lane >> 4) << 4;
  const int r0 = (lane >> 4) << 2;
  const int qwA = qtA * 64 + w * 16;
  const int qwB = qtB * 64 + w * 16;
  char* Psw = (char*)Ps + w * 1024;

  bf16x8 qfA[4], qfB[4];
#pragma unroll
  for (int dblk = 0; dblk < 4; ++dblk) {
    qfA[dblk] = *(const bf16x8*)&Qh[(size_t)(qwA + lr) * 128 + dblk * 32 + (lk2 >> 1)];
    qfB[dblk] = *(const bf16x8*)&Qh[(size_t)(qwB + lr) * 128 + dblk * 32 + (lk2 >> 1)];
  }
  union { uint16_t u[8]; bf16x8 v; } ou;
#pragma unroll
  for (int j = 0; j < 8; ++j) ou.u[j] = 0x3F80;
  const bf16x8 ones = ou.v;
  f32x4 oA[8] = {}, oB[8] = {};
  f32x4 sumA = {}, sumB = {};

  auto stageKV = [&](int tile, int buf) {
    const int kv0 = tile * 64;
    char* Kb = (char*)Ks + (buf << 14);
    char* Vb = (char*)Vs + (buf << 14);
#pragma unroll
    for (int i = 0; i < 4; ++i) {
      int off = i * 4096 + tid * 16;
      int krow = off >> 8;
      int kchunk = (off >> 4) & 15;
      int kcol = (kchunk ^ (krow & 7)) << 3;
      async16(Kh + (size_t)(kv0 + krow) * 128 + kcol, Kb + off);
      int vrow = off >> 7;
      int vchunk = (off >> 4) & 7;
      int vcol = (vchunk ^ (vrow & 7)) << 3;
      async16(Vh + (size_t)vrow * T_ + kv0 + vcol, Vb + off);
    }
  };

  auto tilecompute = [&](const bf16x8* qf, f32x4* o, f32x4* sum, int qw, int kv0, int cur) {
    const char* Kb = (const char*)Ks + (cur << 14);
    const char* Vb = (const char*)Vs + (cur << 14);
#pragma unroll
    for (int prr = 0; prr < 2; ++prr) {
#pragma unroll
      for (int kbi = 0; kbi < 2; ++kbi) {
        int kb = prr * 2 + kbi;
        f32x4 s = {};
        __builtin_amdgcn_s_setprio(1);
#pragma unroll
        for (int dblk = 0; dblk < 4; ++dblk) {
          bf16x8 kf = *(const bf16x8*)(Kb +
              ((kb * 16 + lr) << 8) + ((dblk * 64 + lk2) ^ ((lr & 7) << 4)));
          s = __builtin_amdgcn_mfma_f32_16x16x32_bf16(qf[dblk], kf, s, 0, 0, 0);
        }
        __builtin_amdgcn_s_setprio(0);
        int kval = kv0 + kb * 16 + lr;
#pragma unroll
        for (int r = 0; r < 4; ++r) {
          float pv = (kval <= qw + r0 + r) ? __expf(s[r]) : 0.0f;
          *(uint16_t*)(Psw + (r0 + r) * 64 + (((kbi * 16 + lr) * 2) ^ (r << 4))) = f2bf(pv);
        }
      }
      asm volatile("s_waitcnt lgkmcnt(0)" ::: "memory");
      bf16x8 pa = *(const bf16x8*)(Psw + lr * 64 + (lk2 ^ ((lr & 3) << 4)));
      __builtin_amdgcn_s_setprio(1);
#pragma unroll
      for (int dblk = 0; dblk < 8; ++dblk) {
        bf16x8 vf = *(const bf16x8*)(Vb +
            ((dblk * 16 + lr) << 7) + ((prr * 64 + lk2) ^ ((lr & 7) << 4)));
        o[dblk] = __builtin_amdgcn_mfma_f32_16x16x32_bf16(pa, vf, o[dblk], 0, 0, 0);
      }
      *sum = __builtin_amdgcn_mfma_f32_16x16x32_bf16(pa, ones, *sum, 0, 0, 0);
      __builtin_amdgcn_s_setprio(0);
    }
  };

  stageKV(0, 0);
  asm volatile("s_waitcnt vmcnt(0)" ::: "memory");
  __builtin_amdgcn_s_barrier();
  for (int tile = 0; tile <= qtB; ++tile) {
    const int cur = tile & 1;
    if (tile < qtB) stageKV(tile + 1, cur ^ 1);   // prefetch under compute
    const int kv0 = tile * 64;
    tilecompute(qfB, oB, &sumB, qwB, kv0, cur);
    if (tile <= qtA) tilecompute(qfA, oA, &sumA, qwA, kv0, cur);
    asm volatile("s_waitcnt vmcnt(0)" ::: "memory");  // prefetch landed (cheap now)
    __builtin_amdgcn_s_barrier();
  }

  auto writeout = [&](const f32x4* o, const f32x4& sum, int qw) {
#pragma unroll
    for (int r = 0; r < 4; ++r) {
      float inv = 1.0f / sum[r];
      size_t base = ((size_t)b * T_ + (qw + r0 + r)) * D_ + h * 128 + lr;
#pragma unroll
      for (int dblk = 0; dblk < 8; ++dblk)
        Y[base + dblk * 16] = f2bf(o[dblk][r] * inv);
    }
  };
  writeout(oA, sumA, qwA);
  writeout(oB, sumB, qwB);
}

extern "C" void kernel_launch(void* const* d_in, const int* in_sizes, int n_in,
                              void* d_out, int out_size, void* d_ws, size_t ws_size,
                              hipStream_t stream) {
  (void)in_sizes; (void)n_in; (void)out_size; (void)ws_size;
  const float* q  = (const float*)d_in[0];
  const float* k  = (const float*)d_in[1];
  const float* v  = (const float*)d_in[2];
  const float* Wq = (const float*)d_in[3];
  const float* Wk = (const float*)d_in[4];
  const float* Wv = (const float*)d_in[5];
  const float* Wo = (const float*)d_in[6];
  const float* g  = (const float*)d_in[7];
  float* out = (float*)d_out;
  char* ws = (char*)d_ws;
  const size_t MB = 1ull << 20;
  uint16_t* qb  = (uint16_t*)(ws);             // 16MB; reused as Y after k_proj
  uint16_t* kb  = (uint16_t*)(ws + 16 * MB);   // 16MB
  uint16_t* vb  = (uint16_t*)(ws + 32 * MB);   // 16MB
  uint16_t* Wqb = (uint16_t*)(ws + 48 * MB);   // 8MB
  uint16_t* Wkb = (uint16_t*)(ws + 56 * MB);   // 2MB
  uint16_t* Wvb = (uint16_t*)(ws + 58 * MB);   // 2MB
  uint16_t* Kn  = (uint16_t*)(ws + 60 * MB);   // 4MB
  uint16_t* Vtb = (uint16_t*)(ws + 64 * MB);   // 4MB
  uint16_t* Wob = (uint16_t*)(ws + 68 * MB);   // 8MB (ws high-water: 76MB)
  uint16_t* Qn  = (uint16_t*)d_out;            // 16MB scratch in d_out; dead
                                               // before final GEMM overwrites it
  uint16_t* Y   = qb;

  // 1) convert all seven fp32 inputs in one launch
  k_cvt_all<<<17408, 256, 0, stream>>>(q, k, v, Wq, Wk, Wv, Wo,
                                       qb, kb, vb, Wqb, Wkb, Wvb, Wob);
  // 2) merged Q/K/V projection, balanced 512-block grid, 3-bit LDS swizzle
  k_proj<<<512, 256, 0, stream>>>(qb, kb, vb, Wqb, Wkb, Wvb, Qn, Kn, Vtb, g);
  // 3) attention (reads Qn from d_out, writes Y)
  k_attn<<<B_ * H_ * (T_ / 128), 256, 0, stream>>>(Qn, Kn, Vtb, Y);
  // 4) output projection: 128^2 dbuf + XCD-chunked + 3-bit swizzle (512 blocks)
  k_gemm_bt<<<(B_ * T_ / 128) * (D_ / 128), 256, 0, stream>>>(Y, Wob, out, B_ * T_, D_, D_);
}

// Round 17
// 191.588 us; speedup vs baseline: 1.1332x; 1.0203x over previous
//
#include <hip/hip_runtime.h>
#include <hip/hip_bf16.h>
#include <stdint.h>

#define B_ 2
#define T_ 2048
#define D_ 2048
#define H_ 16
#define KVH_ 4
#define DK_ 128

typedef __bf16 bf16x8 __attribute__((ext_vector_type(8)));
typedef float f32x4 __attribute__((ext_vector_type(4)));
typedef unsigned short u16x8 __attribute__((ext_vector_type(8)));

typedef __attribute__((address_space(1))) void* gas1_t;
typedef __attribute__((address_space(3))) void* gas3_t;

__device__ __forceinline__ uint16_t f2bf(float f) {
  uint32_t u = __builtin_bit_cast(uint32_t, f);
  u += 0x7FFFu + ((u >> 16) & 1u);
  return (uint16_t)(u >> 16);
}

__device__ __forceinline__ void async16(const void* g, void* l) {
  __builtin_amdgcn_global_load_lds((gas1_t)(uintptr_t)g, (gas3_t)l, 16, 0, 0);
}

// ---------------- all-inputs fp32 -> bf16 convert, one launch ----------------
__global__ __launch_bounds__(256) void k_cvt_all(const float* __restrict__ q,
                                                 const float* __restrict__ k,
                                                 const float* __restrict__ v,
                                                 const float* __restrict__ wq,
                                                 const float* __restrict__ wk,
                                                 const float* __restrict__ wv,
                                                 const float* __restrict__ wo,
                                                 uint16_t* __restrict__ qb,
                                                 uint16_t* __restrict__ kb,
                                                 uint16_t* __restrict__ vb,
                                                 uint16_t* __restrict__ wqb,
                                                 uint16_t* __restrict__ wkb,
                                                 uint16_t* __restrict__ wvb,
                                                 uint16_t* __restrict__ wob) {
  int gb = blockIdx.x;
  const float* s; uint16_t* d; int base;
  if (gb < 4096)        { s = q;  d = qb;  base = 0; }
  else if (gb < 8192)   { s = k;  d = kb;  base = 4096; }
  else if (gb < 12288)  { s = v;  d = vb;  base = 8192; }
  else if (gb < 14336)  { s = wq; d = wqb; base = 12288; }
  else if (gb < 14848)  { s = wk; d = wkb; base = 14336; }
  else if (gb < 15360)  { s = wv; d = wvb; base = 14848; }
  else                  { s = wo; d = wob; base = 15360; }
  int i = (gb - base) * 256 + threadIdx.x;
  const float4* s4 = (const float4*)s;
  float4 a = s4[(size_t)i * 2], b = s4[(size_t)i * 2 + 1];
  union { uint16_t u[8]; uint4 v; } o;
  o.u[0] = f2bf(a.x); o.u[1] = f2bf(a.y); o.u[2] = f2bf(a.z); o.u[3] = f2bf(a.w);
  o.u[4] = f2bf(b.x); o.u[5] = f2bf(b.y); o.u[6] = f2bf(b.z); o.u[7] = f2bf(b.w);
  ((uint4*)d)[i] = o.v;
}

// Bank swizzle (3-bit, b128-optimal) for [row][128B] LDS tiles:
// stored 16B-chunk c holds logical chunk c ^ (row&7). A wave's 16-lane service
// group then covers all 8 bank-quads exactly twice (2-way = free). Same
// involution on the global_load_lds SOURCE column and the ds_read address.
// (Rows read are base+lr with base%16==0, so row&7 == lr&7.)

// ---------------- bf16 GEMM (out-proj): 128^2 tile, dbuf, XCD-chunked ----------------
__global__ __launch_bounds__(256) void k_gemm_bt(const uint16_t* __restrict__ A,
                                                 const uint16_t* __restrict__ Bm,
                                                 float* __restrict__ C,
                                                 int M, int N, int K) {
  __shared__ uint16_t As[2 * 128 * 64];
  __shared__ uint16_t Bs[2 * 128 * 64];
  const int tid = threadIdx.x;
  const int x = blockIdx.x & 7, j = blockIdx.x >> 3;   // j in 0..63
  const int m0 = (((x >> 1) << 3) + (j & 7)) << 7;     // mpanel 0..31
  const int n0 = (((x & 1) << 3) + (j >> 3)) << 7;     // ntile 0..15
  const int w = tid >> 6, lane = tid & 63;
  const int wr = (w >> 1) << 6, wc = (w & 1) << 6;
  const int lr = lane & 15;
  const int g16 = ((lane >> 4) << 4);
  const int lsw = (lr & 7) << 4;
  f32x4 acc[4][4] = {};
  const int soff = tid * 16;
  const int scol = ((tid & 7) ^ ((tid >> 3) & 7)) << 3;
  const int srow = tid >> 3;
  const int nk = K >> 6;

  auto stage = [&](int t, int buf) {
    char* Ab = (char*)As + (buf << 14);
    char* Bb = (char*)Bs + (buf << 14);
#pragma unroll
    for (int i = 0; i < 4; ++i) {
      int row = i * 32 + srow;
      async16(A + (size_t)(m0 + row) * K + t * 64 + scol, Ab + i * 4096 + soff);
      async16(Bm + (size_t)(n0 + row) * K + t * 64 + scol, Bb + i * 4096 + soff);
    }
  };

  stage(0, 0);
  asm volatile("s_waitcnt vmcnt(0)" ::: "memory");
  __builtin_amdgcn_s_barrier();
  for (int t = 0; t < nk; ++t) {
    const int cur = t & 1;
    if (t + 1 < nk) stage(t + 1, cur ^ 1);
    const char* Ab = (const char*)As + (cur << 14);
    const char* Bb = (const char*)Bs + (cur << 14);
#pragma unroll
    for (int kk2 = 0; kk2 < 128; kk2 += 64) {
      bf16x8 af[4], bfr[4];
      const int cb = (kk2 + g16) ^ lsw;
#pragma unroll
      for (int m = 0; m < 4; ++m)
        af[m] = *(const bf16x8*)(Ab + (wr + m * 16 + lr) * 128 + cb);
#pragma unroll
      for (int n = 0; n < 4; ++n)
        bfr[n] = *(const bf16x8*)(Bb + (wc + n * 16 + lr) * 128 + cb);
#pragma unroll
      for (int m = 0; m < 4; ++m)
#pragma unroll
        for (int n = 0; n < 4; ++n)
          acc[m][n] = __builtin_amdgcn_mfma_f32_16x16x32_bf16(af[m], bfr[n], acc[m][n], 0, 0, 0);
    }
    asm volatile("s_waitcnt vmcnt(0)" ::: "memory");
    __builtin_amdgcn_s_barrier();
  }
  const int r0 = (lane >> 4) << 2;
  const int c = lane & 15;
#pragma unroll
  for (int m = 0; m < 4; ++m)
#pragma unroll
    for (int n = 0; n < 4; ++n)
#pragma unroll
      for (int r = 0; r < 4; ++r)
        C[(size_t)(m0 + wr + m * 16 + r0 + r) * N + n0 + wc + n * 16 + c] = acc[m][n][r];
}

// ---------------- merged QKV projection, balanced 512-block grid ----------------
// [0,256):   Q, M-paired 256x128 tiles, XCD-chunked  (heavy)
// [256,384): V, unpaired 128x128 -> transpose        (light)
// [384,512): K, unpaired 128x128 -> l2norm           (light)
__global__ __launch_bounds__(256, 2) void k_proj(const uint16_t* __restrict__ qb,
                                                 const uint16_t* __restrict__ kb,
                                                 const uint16_t* __restrict__ vb,
                                                 const uint16_t* __restrict__ Wqb,
                                                 const uint16_t* __restrict__ Wkb,
                                                 const uint16_t* __restrict__ Wvb,
                                                 uint16_t* __restrict__ Qn,
                                                 uint16_t* __restrict__ Kn,
                                                 uint16_t* __restrict__ Vt,
                                                 const float* __restrict__ g) {
  __shared__ char smem[49152];   // Q: Aa/Ab/B 16KB each. KV: A@0, B@16384. tr aliases.
  __shared__ float ssred[2][256];
  const int bid = blockIdx.x;
  const int tid = threadIdx.x;
  const int w = tid >> 6, lane = tid & 63;
  const int wr = (w >> 1) << 6, wc = (w & 1) << 6;
  const int lr = lane & 15;
  const int g16 = ((lane >> 4) << 4);
  const int lsw = (lr & 7) << 4;
  const int soff = tid * 16;
  const int scol = ((tid & 7) ^ ((tid >> 3) & 7)) << 3;
  const int srow = tid >> 3;
  const int g4 = lane >> 4;
  const int r04 = g4 << 2;

  if (bid < 256) {
    // ================= Q: M-paired =================
    const uint16_t* A = qb;
    const uint16_t* Bw = Wqb;
    const int x = bid & 7, jj = bid >> 3;
    const int m0 = (((x >> 1) << 2) + (jj & 3)) << 8;      // 16 mpanels of 256 rows
    const int n0 = (((x & 1) << 3) + (jj >> 2)) << 7;      // 16 ntiles
    f32x4 acc[8][4] = {};
    for (int t = 0; t < 32; ++t) {
#pragma unroll
      for (int i = 0; i < 4; ++i) {
        int row = i * 32 + srow;
        async16(A + (size_t)(m0 + row) * 2048 + t * 64 + scol, smem + i * 4096 + soff);
        async16(A + (size_t)(m0 + 128 + row) * 2048 + t * 64 + scol, smem + 16384 + i * 4096 + soff);
        async16(Bw + (size_t)(n0 + row) * 2048 + t * 64 + scol, smem + 32768 + i * 4096 + soff);
      }
      __syncthreads();
#pragma unroll
      for (int kk2 = 0; kk2 < 128; kk2 += 64) {
        bf16x8 aA[4], aB[4], bfr[4];
        const int cb = (kk2 + g16) ^ lsw;
#pragma unroll
        for (int m = 0; m < 4; ++m) {
          aA[m] = *(const bf16x8*)(smem + (wr + m * 16 + lr) * 128 + cb);
          aB[m] = *(const bf16x8*)(smem + 16384 + (wr + m * 16 + lr) * 128 + cb);
        }
#pragma unroll
        for (int n = 0; n < 4; ++n)
          bfr[n] = *(const bf16x8*)(smem + 32768 + (wc + n * 16 + lr) * 128 + cb);
#pragma unroll
        for (int m = 0; m < 4; ++m)
#pragma unroll
          for (int n = 0; n < 4; ++n) {
            acc[m][n] = __builtin_amdgcn_mfma_f32_16x16x32_bf16(aA[m], bfr[n], acc[m][n], 0, 0, 0);
            acc[m + 4][n] = __builtin_amdgcn_mfma_f32_16x16x32_bf16(aB[m], bfr[n], acc[m + 4][n], 0, 0, 0);
          }
      }
      __syncthreads();
    }
    // ---- fused l2norm*g epilogue over 256 rows ----
    const int b = m0 >> 11;
    const int t0 = m0 & (T_ - 1);
    const int h = n0 >> 7;
    float ss[8][4];
#pragma unroll
    for (int m = 0; m < 8; ++m)
#pragma unroll
      for (int r = 0; r < 4; ++r) {
        float s = 0.f;
#pragma unroll
        for (int n = 0; n < 4; ++n) s += acc[m][n][r] * acc[m][n][r];
        ss[m][r] = s;
      }
#pragma unroll
    for (int mask = 1; mask < 16; mask <<= 1)
#pragma unroll
      for (int m = 0; m < 8; ++m)
#pragma unroll
        for (int r = 0; r < 4; ++r) ss[m][r] += __shfl_xor(ss[m][r], mask);
#pragma unroll
    for (int m = 0; m < 8; ++m)
#pragma unroll
      for (int r = 0; r < 4; ++r)
        if (lr == (((m & 3) << 2) | r))
          ssred[w & 1][(m >> 2) * 128 + wr + (m & 3) * 16 + g4 * 4 + r] = ss[m][r];
    __syncthreads();
    const float gmul = g[h] * 0.08838834764831845f;   // fold 1/sqrt(128)
#pragma unroll
    for (int m = 0; m < 8; ++m)
#pragma unroll
      for (int r = 0; r < 4; ++r) {
        int row = (m >> 2) * 128 + wr + (m & 3) * 16 + g4 * 4 + r;
        float tot = ssred[0][row] + ssred[1][row];
        float scl = gmul / fmaxf(sqrtf(tot), 1e-12f);
        size_t base = ((size_t)(b * H_ + h) * T_ + (t0 + row)) * 128;
#pragma unroll
        for (int n = 0; n < 4; ++n)
          Qn[base + wc + n * 16 + lr] = f2bf(acc[m][n][r] * scl);
      }
  } else {
    // ================= K/V: unpaired 128^2 =================
    const int mode = (bid < 384) ? 2 : 1;          // 2=V, 1=K
    const int lb = (mode == 2) ? bid - 256 : bid - 384;
    const uint16_t* A = (mode == 2) ? vb : kb;
    const uint16_t* Bw = (mode == 2) ? Wvb : Wkb;
    const int x = lb & 7, jj = lb >> 3;            // jj 0..15
    const int m0 = (((x >> 1) << 3) + (jj & 7)) << 7;   // 32 mpanels of 128 rows
    const int n0 = (((x & 1) << 1) + (jj >> 3)) << 7;   // 4 ntiles
    f32x4 acc[4][4] = {};
    for (int t = 0; t < 32; ++t) {
#pragma unroll
      for (int i = 0; i < 4; ++i) {
        int row = i * 32 + srow;
        async16(A + (size_t)(m0 + row) * 2048 + t * 64 + scol, smem + i * 4096 + soff);
        async16(Bw + (size_t)(n0 + row) * 2048 + t * 64 + scol, smem + 16384 + i * 4096 + soff);
      }
      __syncthreads();
#pragma unroll
      for (int kk2 = 0; kk2 < 128; kk2 += 64) {
        bf16x8 af[4], bfr[4];
        const int cb = (kk2 + g16) ^ lsw;
#pragma unroll
        for (int m = 0; m < 4; ++m)
          af[m] = *(const bf16x8*)(smem + (wr + m * 16 + lr) * 128 + cb);
#pragma unroll
        for (int n = 0; n < 4; ++n)
          bfr[n] = *(const bf16x8*)(smem + 16384 + (wc + n * 16 + lr) * 128 + cb);
#pragma unroll
        for (int m = 0; m < 4; ++m)
#pragma unroll
          for (int n = 0; n < 4; ++n)
            acc[m][n] = __builtin_amdgcn_mfma_f32_16x16x32_bf16(af[m], bfr[n], acc[m][n], 0, 0, 0);
      }
      __syncthreads();
    }
    const int b = m0 >> 11;
    const int t0 = m0 & (T_ - 1);
    const int h = n0 >> 7;
    if (mode == 1) {
      // ---- fused l2norm epilogue (K) ----
      float ss[4][4];
#pragma unroll
      for (int m = 0; m < 4; ++m)
#pragma unroll
        for (int r = 0; r < 4; ++r) {
          float s = 0.f;
#pragma unroll
          for (int n = 0; n < 4; ++n) s += acc[m][n][r] * acc[m][n][r];
          ss[m][r] = s;
        }
#pragma unroll
      for (int mask = 1; mask < 16; mask <<= 1)
#pragma unroll
        for (int m = 0; m < 4; ++m)
#pragma unroll
          for (int r = 0; r < 4; ++r) ss[m][r] += __shfl_xor(ss[m][r], mask);
#pragma unroll
      for (int m = 0; m < 4; ++m)
#pragma unroll
        for (int r = 0; r < 4; ++r)
          if (lr == (m << 2 | r)) ssred[w & 1][wr + m * 16 + g4 * 4 + r] = ss[m][r];
      __syncthreads();
#pragma unroll
      for (int m = 0; m < 4; ++m)
#pragma unroll
        for (int r = 0; r < 4; ++r) {
          int row = wr + m * 16 + g4 * 4 + r;
          float tot = ssred[0][row] + ssred[1][row];
          float scl = 1.0f / fmaxf(sqrtf(tot), 1e-12f);
          size_t base = ((size_t)(b * KVH_ + h) * T_ + (t0 + row)) * 128;
#pragma unroll
          for (int n = 0; n < 4; ++n)
            Kn[base + wc + n * 16 + lr] = f2bf(acc[m][n][r] * scl);
        }
    } else {
      // ---- fused V-transpose epilogue ----
      uint16_t* tr = (uint16_t*)smem;  // [col 0..127][trow 0..127], stride 132
#pragma unroll
      for (int m = 0; m < 4; ++m)
#pragma unroll
        for (int n = 0; n < 4; ++n)
#pragma unroll
          for (int r = 0; r < 4; ++r)
            tr[(wc + n * 16 + lr) * 132 + (wr + m * 16 + r04 + r)] = f2bf(acc[m][n][r]);
      __syncthreads();
      const int qd = tid & 3;
#pragma unroll
      for (int dd = 0; dd < 2; ++dd) {
        int d = (tid >> 2) + dd * 64;
        uint16_t* dst = Vt + ((size_t)(b * KVH_ + h) * 128 + d) * T_ + t0 + qd * 32;
        const uint16_t* srcl = &tr[d * 132 + qd * 32];
#pragma unroll
        for (int j = 0; j < 8; ++j)
          *(ushort4*)(dst + j * 4) = *(const ushort4*)(srcl + j * 4);
      }
    }
  }
}

// ---------------- causal GQA flash attention, paired q-tiles, dbuf K/V ----------------
__global__ __launch_bounds__(256) void k_attn(const uint16_t* __restrict__ Qn,
                                              const uint16_t* __restrict__ Kn,
                                              const uint16_t* __restrict__ Vt,
                                              uint16_t* __restrict__ Y) {
  __shared__ uint16_t Ks[2 * 64 * 128];
  __shared__ uint16_t Vs[2 * 128 * 64];
  __shared__ uint16_t Ps[4 * 16 * 32];
  const int npair = T_ / 128;              // 16
  const int pair_id = blockIdx.x % npair;
  const int bh = blockIdx.x / npair;
  const int h = bh % H_;
  const int b = bh / H_;
  const int kvh = h >> 2;
  const int qtA = pair_id;                 // light tile
  const int qtB = (T_ / 64) - 1 - pair_id; // heavy tile
  const uint16_t* Qh = Qn + ((size_t)(b * H_ + h) * T_) * 128;
  const uint16_t* Kh = Kn + ((size_t)(b * KVH_ + kvh) * T_) * 128;
  const uint16_t* Vh = Vt + ((size_t)(b * KVH_ + kvh) * 128) * T_;
  const int tid = threadIdx.x;
  const int w = tid >> 6, lane = tid & 63;
  const int lr = lane & 15;
  const int lk2 = (lane >> 4) << 4;
  const int r0 = (lane >> 4) << 2;
  const int qwA = qtA * 64 + w * 16;
  const int qwB = qtB * 64 + w * 16;
  char* Psw = (char*)Ps + w * 1024;

  bf16x8 qfA[4], qfB[4];
#pragma unroll
  for (int dblk = 0; dblk < 4; ++dblk) {
    qfA[dblk] = *(const bf16x8*)&Qh[(size_t)(qwA + lr) * 128 + dblk * 32 + (lk2 >> 1)];
    qfB[dblk] = *(const bf16x8*)&Qh[(size_t)(qwB + lr) * 128 + dblk * 32 + (lk2 >> 1)];
  }
  union { uint16_t u[8]; bf16x8 v; } ou;
#pragma unroll
  for (int j = 0; j < 8; ++j) ou.u[j] = 0x3F80;
  const bf16x8 ones = ou.v;
  f32x4 oA[8] = {}, oB[8] = {};
  f32x4 sumA = {}, sumB = {};

  auto stageKV = [&](int tile, int buf) {
    const int kv0 = tile * 64;
    char* Kb = (char*)Ks + (buf << 14);
    char* Vb = (char*)Vs + (buf << 14);
#pragma unroll
    for (int i = 0; i < 4; ++i) {
      int off = i * 4096 + tid * 16;
      int krow = off >> 8;
      int kchunk = (off >> 4) & 15;
      int kcol = (kchunk ^ (krow & 7)) << 3;
      async16(Kh + (size_t)(kv0 + krow) * 128 + kcol, Kb + off);
      int vrow = off >> 7;
      int vchunk = (off >> 4) & 7;
      int vcol = (vchunk ^ (vrow & 7)) << 3;
      async16(Vh + (size_t)vrow * T_ + kv0 + vcol, Vb + off);
    }
  };

  auto tilecompute = [&](const bf16x8* qf, f32x4* o, f32x4* sum, int qw, int kv0, int cur) {
    const char* Kb = (const char*)Ks + (cur << 14);
    const char* Vb = (const char*)Vs + (cur << 14);
#pragma unroll
    for (int prr = 0; prr < 2; ++prr) {
#pragma unroll
      for (int kbi = 0; kbi < 2; ++kbi) {
        int kb = prr * 2 + kbi;
        f32x4 s = {};
#pragma unroll
        for (int dblk = 0; dblk < 4; ++dblk) {
          bf16x8 kf = *(const bf16x8*)(Kb +
              ((kb * 16 + lr) << 8) + ((dblk * 64 + lk2) ^ ((lr & 7) << 4)));
          s = __builtin_amdgcn_mfma_f32_16x16x32_bf16(qf[dblk], kf, s, 0, 0, 0);
        }
        int kval = kv0 + kb * 16 + lr;
#pragma unroll
        for (int r = 0; r < 4; ++r) {
          float pv = (kval <= qw + r0 + r) ? __expf(s[r]) : 0.0f;
          *(uint16_t*)(Psw + (r0 + r) * 64 + (((kbi * 16 + lr) * 2) ^ (r << 4))) = f2bf(pv);
        }
      }
      asm volatile("s_waitcnt lgkmcnt(0)" ::: "memory");
      bf16x8 pa = *(const bf16x8*)(Psw + lr * 64 + (lk2 ^ ((lr & 3) << 4)));
#pragma unroll
      for (int dblk = 0; dblk < 8; ++dblk) {
        bf16x8 vf = *(const bf16x8*)(Vb +
            ((dblk * 16 + lr) << 7) + ((prr * 64 + lk2) ^ ((lr & 7) << 4)));
        o[dblk] = __builtin_amdgcn_mfma_f32_16x16x32_bf16(pa, vf, o[dblk], 0, 0, 0);
      }
      *sum = __builtin_amdgcn_mfma_f32_16x16x32_bf16(pa, ones, *sum, 0, 0, 0);
    }
  };

  stageKV(0, 0);
  asm volatile("s_waitcnt vmcnt(0)" ::: "memory");
  __builtin_amdgcn_s_barrier();
  for (int tile = 0; tile <= qtB; ++tile) {
    const int cur = tile & 1;
    if (tile < qtB) stageKV(tile + 1, cur ^ 1);   // prefetch under compute
    const int kv0 = tile * 64;
    tilecompute(qfB, oB, &sumB, qwB, kv0, cur);
    if (tile <= qtA) tilecompute(qfA, oA, &sumA, qwA, kv0, cur);
    asm volatile("s_waitcnt vmcnt(0)" ::: "memory");  // prefetch landed (cheap now)
    __builtin_amdgcn_s_barrier();
  }

  auto writeout = [&](const f32x4* o, const f32x4& sum, int qw) {
#pragma unroll
    for (int r = 0; r < 4; ++r) {
      float inv = 1.0f / sum[r];
      size_t base = ((size_t)b * T_ + (qw + r0 + r)) * D_ + h * 128 + lr;
#pragma unroll
      for (int dblk = 0; dblk < 8; ++dblk)
        Y[base + dblk * 16] = f2bf(o[dblk][r] * inv);
    }
  };
  writeout(oA, sumA, qwA);
  writeout(oB, sumB, qwB);
}

extern "C" void kernel_launch(void* const* d_in, const int* in_sizes, int n_in,
                              void* d_out, int out_size, void* d_ws, size_t ws_size,
                              hipStream_t stream) {
  (void)in_sizes; (void)n_in; (void)out_size; (void)ws_size;
  const float* q  = (const float*)d_in[0];
  const float* k  = (const float*)d_in[1];
  const float* v  = (const float*)d_in[2];
  const float* Wq = (const float*)d_in[3];
  const float* Wk = (const float*)d_in[4];
  const float* Wv = (const float*)d_in[5];
  const float* Wo = (const float*)d_in[6];
  const float* g  = (const float*)d_in[7];
  float* out = (float*)d_out;
  char* ws = (char*)d_ws;
  const size_t MB = 1ull << 20;
  uint16_t* qb  = (uint16_t*)(ws);             // 16MB; reused as Y after k_proj
  uint16_t* kb  = (uint16_t*)(ws + 16 * MB);   // 16MB
  uint16_t* vb  = (uint16_t*)(ws + 32 * MB);   // 16MB
  uint16_t* Wqb = (uint16_t*)(ws + 48 * MB);   // 8MB
  uint16_t* Wkb = (uint16_t*)(ws + 56 * MB);   // 2MB
  uint16_t* Wvb = (uint16_t*)(ws + 58 * MB);   // 2MB
  uint16_t* Kn  = (uint16_t*)(ws + 60 * MB);   // 4MB
  uint16_t* Vtb = (uint16_t*)(ws + 64 * MB);   // 4MB
  uint16_t* Wob = (uint16_t*)(ws + 68 * MB);   // 8MB (ws high-water: 76MB)
  uint16_t* Qn  = (uint16_t*)d_out;            // 16MB scratch in d_out; dead
                                               // before final GEMM overwrites it
  uint16_t* Y   = qb;

  // 1) convert all seven fp32 inputs in one launch
  k_cvt_all<<<17408, 256, 0, stream>>>(q, k, v, Wq, Wk, Wv, Wo,
                                       qb, kb, vb, Wqb, Wkb, Wvb, Wob);
  // 2) merged Q/K/V projection, balanced 512-block grid, 3-bit LDS swizzle
  k_proj<<<512, 256, 0, stream>>>(qb, kb, vb, Wqb, Wkb, Wvb, Qn, Kn, Vtb, g);
  // 3) attention (reads Qn from d_out, writes Y)
  k_attn<<<B_ * H_ * (T_ / 128), 256, 0, stream>>>(Qn, Kn, Vtb, Y);
  // 4) output projection: 128^2 dbuf + XCD-chunked + 3-bit swizzle (512 blocks)
  k_gemm_bt<<<(B_ * T_ / 128) * (D_ / 128), 256, 0, stream>>>(Y, Wob, out, B_ * T_, D_, D_);
}